// Round 8
// baseline (227.122 us; speedup 1.0000x reference)
//
#include <hip/hip_runtime.h>
#include <math.h>

#define DIM 128
#define KCODES 1024
#define NROWS 65536

typedef short bf16x8 __attribute__((ext_vector_type(8)));
typedef float f32x4 __attribute__((ext_vector_type(4)));

// ---- workspace float-index layout ----
// [WS_COUNTS, WS_ESUM end) is one contiguous zeroed region (528384 B)
#define WS_COUNTS 0        // 1024 f: batch histogram
#define WS_ESUM   1024     // 131072 f: segment sums (atomic accum)
#define WS_IOFF   132096   // 1024 int: exclusive offsets (bumped by sortscatter)
#define WS_TOTAL  133120   // 1 f
#define WS_ENORM2 133124   // 1024 f: 512 - 0.5*||e||^2
#define WS_EBF    134148   // 131072 bf16 (= 65536 float slots), 16B aligned
#define WS_CAND   199684   // 65536 uint4, 16B aligned
#define WS_WIN    461828   // 65536 int
#define WS_SORTED 527364   // 65536 int
#define WS_SCODE  592900   // 65536 int

// ---- output float layout ----
#define OFF_Q   0
#define OFF_IND 8388608
#define OFF_NCS 8454144
#define OFF_NEA 8455168
#define OFF_NE  8586240

#define LDST 136  // LDS row stride in bf16 units (128 + 8 pad)

static __device__ __forceinline__ unsigned short f2bf(float f) {
    unsigned u = __float_as_uint(f);
    unsigned r = (u + 0x7FFFu + ((u >> 16) & 1u)) >> 16;  // RTN-even
    return (unsigned short)r;
}

// ============ kernel 1: embed -> bf16 copy + shifted half-norms ============
__global__ __launch_bounds__(64) void k_prep(const float* __restrict__ embed,
                                             unsigned short* __restrict__ ebf,
                                             float* __restrict__ en2) {
    int k = blockIdx.x;
    int l = threadIdx.x;
    float2 v = *(const float2*)&embed[(size_t)k * DIM + l * 2];
    ushort2 b;
    b.x = f2bf(v.x);
    b.y = f2bf(v.y);
    *(ushort2*)&ebf[k * DIM + l * 2] = b;
    float s = v.x * v.x + v.y * v.y;
    #pragma unroll
    for (int off = 32; off; off >>= 1) s += __shfl_xor(s, off);
    if (l == 0) en2[k] = 512.0f - 0.5f * s;
}

// ============ kernel 2: MFMA scoring, 4 candidates per row ============
__global__ __launch_bounds__(256, 2) void k_score(const float* __restrict__ x,
                                                  const unsigned short* __restrict__ ebf,
                                                  const float* __restrict__ en2g,
                                                  uint4* __restrict__ cand) {
    __shared__ unsigned short xbuf[128 * LDST];
    __shared__ unsigned short ebuf[128 * LDST];
    __shared__ float en2s[KCODES];

    const int tid = threadIdx.x;
    const int row0 = blockIdx.x * 128;

    #pragma unroll
    for (int i = 0; i < 4; ++i) en2s[i * 256 + tid] = en2g[i * 256 + tid];

    #pragma unroll
    for (int i = 0; i < 16; ++i) {
        int idx4 = i * 256 + tid;
        int lin = idx4 * 4;
        int r = lin >> 7, d = lin & 127;
        float4 v = *(const float4*)&x[(size_t)(row0 + r) * DIM + d];
        ushort4 b;
        b.x = f2bf(v.x); b.y = f2bf(v.y); b.z = f2bf(v.z); b.w = f2bf(v.w);
        *(ushort4*)&xbuf[r * LDST + d] = b;
    }

    const int lane = tid & 63;
    const int wv = tid >> 6;
    const int ch = wv & 1;
    const int rh = (wv >> 1) * 64;
    const int l15 = lane & 15;
    const int q = lane >> 4;

    float m1[4][4], m2[4][4];
    #pragma unroll
    for (int a = 0; a < 4; ++a)
        #pragma unroll
        for (int b = 0; b < 4; ++b) { m1[a][b] = 0.0f; m2[a][b] = 0.0f; }

    for (int ct = 0; ct < 8; ++ct) {
        const int c0 = ct * 128;
        __syncthreads();
        #pragma unroll
        for (int i = 0; i < 8; ++i) {
            int idx8 = i * 256 + tid;
            int r = idx8 >> 4;
            int d = (idx8 & 15) * 8;
            uint4 v = *(const uint4*)&ebf[(size_t)(c0 + r) * DIM + d];
            *(uint4*)&ebuf[r * LDST + d] = v;
        }
        __syncthreads();

        f32x4 acc[4][4];
        #pragma unroll
        for (int a = 0; a < 4; ++a)
            #pragma unroll
            for (int b = 0; b < 4; ++b) acc[a][b] = (f32x4){0.f, 0.f, 0.f, 0.f};

        #pragma unroll
        for (int ks = 0; ks < 4; ++ks) {
            bf16x8 af[4], bf[4];
            #pragma unroll
            for (int t = 0; t < 4; ++t)
                af[t] = *(const bf16x8*)&xbuf[(rh + t * 16 + l15) * LDST + ks * 32 + q * 8];
            #pragma unroll
            for (int t = 0; t < 4; ++t)
                bf[t] = *(const bf16x8*)&ebuf[(ch * 64 + t * 16 + l15) * LDST + ks * 32 + q * 8];
            #pragma unroll
            for (int rt = 0; rt < 4; ++rt)
                #pragma unroll
                for (int cl = 0; cl < 4; ++cl)
                    acc[rt][cl] = __builtin_amdgcn_mfma_f32_16x16x32_bf16(af[rt], bf[cl],
                                                                          acc[rt][cl], 0, 0, 0);
        }

        #pragma unroll
        for (int cl = 0; cl < 4; ++cl) {
            int code = c0 + ch * 64 + cl * 16 + l15;
            float en = en2s[code];
            unsigned cu = (unsigned)code;
            #pragma unroll
            for (int rt = 0; rt < 4; ++rt)
                #pragma unroll
                for (int rg = 0; rg < 4; ++rg) {
                    float s = acc[rt][cl][rg] + en;
                    float kf = __uint_as_float((__float_as_uint(s) & ~1023u) | cu);
                    float lo = fminf(m1[rt][rg], kf);
                    m1[rt][rg] = fmaxf(m1[rt][rg], kf);
                    m2[rt][rg] = fmaxf(m2[rt][rg], lo);
                }
        }
    }

    __syncthreads();
    float* scratch = (float*)xbuf;
    #pragma unroll
    for (int rt = 0; rt < 4; ++rt)
        #pragma unroll
        for (int rg = 0; rg < 4; ++rg) {
            float a1 = m1[rt][rg], a2 = m2[rt][rg];
            #pragma unroll
            for (int off = 1; off <= 8; off <<= 1) {
                float o1 = __shfl_xor(a1, off);
                float o2 = __shfl_xor(a2, off);
                float lo = fminf(a1, o1);
                a1 = fmaxf(a1, o1);
                a2 = fmaxf(fmaxf(a2, o2), lo);
            }
            if (l15 == 0) {
                int row = rh + rt * 16 + q * 4 + rg;
                scratch[row * 4 + ch * 2 + 0] = a1;
                scratch[row * 4 + ch * 2 + 1] = a2;
            }
        }
    __syncthreads();
    if (tid < 128) {
        const float* p = &scratch[tid * 4];
        uint4 c;
        c.x = __float_as_uint(p[0]) & 1023u;
        c.y = __float_as_uint(p[1]) & 1023u;
        c.z = __float_as_uint(p[2]) & 1023u;
        c.w = __float_as_uint(p[3]) & 1023u;
        cand[row0 + tid] = c;
    }
}

// ============ kernel 3: fp64 rescore ONLY (16 lanes/row) ============
// Writes just win_arr + counts. Q/ind production moved to k_quant so this
// kernel is pure-read (WRITE <1MB); rounds 5-7 showed mixing the gather with
// the 33MB streaming Q write measured ~200MB WRITE_SIZE regardless of store
// layout.
__global__ __launch_bounds__(256) void k_pick(const float* __restrict__ x,
                                              const float* __restrict__ embed,
                                              const uint4* __restrict__ cand,
                                              float* __restrict__ counts,
                                              int* __restrict__ win_arr) {
    const int tid = threadIdx.x;
    const int sub = tid & 15;
    const int row = blockIdx.x * 16 + (tid >> 4);

    uint4 cp = cand[row];
    int ci[4] = {(int)cp.x, (int)cp.y, (int)cp.z, (int)cp.w};

    const float* xr = &x[(size_t)row * DIM + sub * 4];
    float4 xa = *(const float4*)xr;
    float4 xb = *(const float4*)(xr + 64);

    double d[4];
    #pragma unroll
    for (int j = 0; j < 4; ++j) {
        const float* er = &embed[(size_t)ci[j] * DIM + sub * 4];
        float4 ea4 = *(const float4*)er;
        float4 eb4 = *(const float4*)(er + 64);
        double t0 = (double)xa.x - (double)ea4.x;
        double t1 = (double)xa.y - (double)ea4.y;
        double t2 = (double)xa.z - (double)ea4.z;
        double t3 = (double)xa.w - (double)ea4.w;
        double t4 = (double)xb.x - (double)eb4.x;
        double t5 = (double)xb.y - (double)eb4.y;
        double t6 = (double)xb.z - (double)eb4.z;
        double t7 = (double)xb.w - (double)eb4.w;
        d[j] = ((t0 * t0 + t1 * t1) + (t2 * t2 + t3 * t3)) +
               ((t4 * t4 + t5 * t5) + (t6 * t6 + t7 * t7));
    }
    #pragma unroll
    for (int off = 1; off <= 8; off <<= 1) {
        #pragma unroll
        for (int j = 0; j < 4; ++j) d[j] += __shfl_xor(d[j], off);
    }

    int win = ci[0];
    double dw = d[0];
    #pragma unroll
    for (int j = 1; j < 4; ++j) {
        bool b = (d[j] < dw) || (d[j] == dw && ci[j] < win);
        dw = b ? d[j] : dw;
        win = b ? ci[j] : win;
    }

    if (sub == 0) {
        win_arr[row] = win;
        atomicAdd(&counts[win], 1.0f);
    }
}

// ============ kernel 3b: quantize gather + ind write ============
// Round-4-proven store pattern: one 512B dense run per wave-iteration
// (float2/lane). embed is L2-resident (512KB); win is wave-uniform scalar.
__global__ __launch_bounds__(256) void k_quant(const float* __restrict__ embed,
                                               const int* __restrict__ win_arr,
                                               float* __restrict__ out) {
    const int tid = threadIdx.x;
    const int lane = tid & 63;
    const int wv = tid >> 6;
    const int rowb = blockIdx.x * 64 + wv * 16;

    if (tid < 64) {
        int r = blockIdx.x * 64 + tid;
        out[OFF_IND + r] = (float)win_arr[r];
    }

    #pragma unroll 4
    for (int i = 0; i < 16; ++i) {
        int row = rowb + i;
        int w = win_arr[row];  // wave-uniform
        float2 v = *(const float2*)&embed[(size_t)w * DIM + lane * 2];
        *(float2*)&out[OFF_Q + (size_t)row * DIM + lane * 2] = v;
    }
}

// ============ kernel 4: shuffle-scan offsets + new_cluster_size + total ============
__global__ __launch_bounds__(1024) void k_offsets(const float* __restrict__ cs,
                                                  float* __restrict__ out,
                                                  float* __restrict__ ws) {
    __shared__ int wsum[16];
    __shared__ float wtot[16];
    const float* counts = ws + WS_COUNTS;
    int* ioff = (int*)(ws + WS_IOFF);

    int t = threadIdx.x;
    int lane = t & 63, w = t >> 6;
    float cf = counts[t];
    int c = (int)cf;
    float ncs = cs[t] * 0.99f + 0.01f * cf;
    out[OFF_NCS + t] = ncs;

    int v = c;
    #pragma unroll
    for (int off = 1; off < 64; off <<= 1) {
        int o = __shfl_up(v, off);
        if (lane >= off) v += o;
    }
    float nf = ncs;
    #pragma unroll
    for (int off = 32; off; off >>= 1) nf += __shfl_xor(nf, off);

    if (lane == 63) wsum[w] = v;
    if (lane == 0) wtot[w] = nf;
    __syncthreads();

    int base = 0;
    for (int i = 0; i < w; ++i) base += wsum[i];
    ioff[t] = base + v - c;

    if (t == 0) {
        float tt = 0.f;
        for (int i = 0; i < 16; ++i) tt += wtot[i];
        ws[WS_TOTAL] = tt;
    }
}

// ============ kernel 5: scatter rows into code-sorted order ============
__global__ __launch_bounds__(256) void k_sortscatter(const int* __restrict__ win_arr,
                                                     int* __restrict__ ioff,
                                                     int* __restrict__ sorted,
                                                     int* __restrict__ scode) {
    int row = blockIdx.x * 256 + threadIdx.x;
    int w = win_arr[row];
    int pos = atomicAdd(&ioff[w], 1);
    sorted[pos] = row;
    scode[pos] = w;
}

// ============ kernel 6: chunked run-length segment sum (skew-proof) ============
__global__ __launch_bounds__(256) void k_segsum(const float* __restrict__ x,
                                                const int* __restrict__ sorted,
                                                const int* __restrict__ scode,
                                                float* __restrict__ esum) {
    const int lane = threadIdx.x & 63;
    const int wv = threadIdx.x >> 6;
    const int base = blockIdx.x * 64 + wv * 16;

    int p = base + (lane & 15);
    int srow = sorted[p];
    int sc = scode[p];

    float ax = 0.f, ay = 0.f;
    int cur = __shfl(sc, 0);

    #pragma unroll
    for (int j = 0; j < 16; ++j) {
        int row = __shfl(srow, j);
        int c = __shfl(sc, j);
        if (c != cur) {
            atomicAdd(&esum[cur * DIM + lane * 2], ax);
            atomicAdd(&esum[cur * DIM + lane * 2 + 1], ay);
            ax = 0.f; ay = 0.f;
            cur = c;
        }
        float2 v = *(const float2*)&x[(size_t)row * DIM + lane * 2];
        ax += v.x;
        ay += v.y;
    }
    atomicAdd(&esum[cur * DIM + lane * 2], ax);
    atomicAdd(&esum[cur * DIM + lane * 2 + 1], ay);
}

// ============ kernel 7: new_embed_avg + new_embed ============
__global__ __launch_bounds__(256) void k_embed(const float* __restrict__ ea,
                                               const float* __restrict__ ws,
                                               float* __restrict__ out) {
    int i = blockIdx.x * 256 + threadIdx.x;
    int k = i >> 7;
    float nea = ea[i] * 0.99f + 0.01f * ws[WS_ESUM + i];
    out[OFF_NEA + i] = nea;
    float total = ws[WS_TOTAL];
    float ncs = out[OFF_NCS + k];
    float sm = (ncs + 1e-5f) / (total + 1024.0f * 1e-5f);
    out[OFF_NE + i] = nea / (sm * total);
}

extern "C" void kernel_launch(void* const* d_in, const int* in_sizes, int n_in,
                              void* d_out, int out_size, void* d_ws, size_t ws_size,
                              hipStream_t stream) {
    const float* x     = (const float*)d_in[0];
    const float* embed = (const float*)d_in[1];
    const float* cs    = (const float*)d_in[2];
    const float* ea    = (const float*)d_in[3];
    float* out = (float*)d_out;
    float* ws  = (float*)d_ws;

    hipMemsetAsync(d_ws, 0, (size_t)(1024 + 131072) * 4, stream);

    k_prep<<<KCODES, 64, 0, stream>>>(embed, (unsigned short*)(ws + WS_EBF), ws + WS_ENORM2);
    k_score<<<NROWS / 128, 256, 0, stream>>>(x, (const unsigned short*)(ws + WS_EBF),
                                             ws + WS_ENORM2, (uint4*)(ws + WS_CAND));
    k_pick<<<NROWS / 16, 256, 0, stream>>>(x, embed, (const uint4*)(ws + WS_CAND),
                                           ws + WS_COUNTS, (int*)(ws + WS_WIN));
    k_quant<<<NROWS / 64, 256, 0, stream>>>(embed, (const int*)(ws + WS_WIN), out);
    k_offsets<<<1, 1024, 0, stream>>>(cs, out, ws);
    k_sortscatter<<<NROWS / 256, 256, 0, stream>>>((const int*)(ws + WS_WIN),
                                                   (int*)(ws + WS_IOFF),
                                                   (int*)(ws + WS_SORTED),
                                                   (int*)(ws + WS_SCODE));
    k_segsum<<<1024, 256, 0, stream>>>(x, (const int*)(ws + WS_SORTED),
                                       (const int*)(ws + WS_SCODE), ws + WS_ESUM);
    k_embed<<<131072 / 256, 256, 0, stream>>>(ea, ws, out);
}

// Round 9
// 193.409 us; speedup vs baseline: 1.1743x; 1.1743x over previous
//
#include <hip/hip_runtime.h>
#include <math.h>

#define DIM 128
#define KCODES 1024
#define NROWS 65536

typedef short bf16x8 __attribute__((ext_vector_type(8)));
typedef float f32x4 __attribute__((ext_vector_type(4)));

// ---- workspace float-index layout ----
// [WS_COUNTS, WS_ESUM end) is one contiguous zeroed region (528384 B)
#define WS_COUNTS 0        // 1024 f: batch histogram
#define WS_ESUM   1024     // 131072 f: segment sums (atomic accum)
#define WS_IOFF   132096   // 1024 int: exclusive offsets (bumped by sortscatter)
#define WS_TOTAL  133120   // 1 f
#define WS_ENORM2 133124   // 1024 f: 512 - 0.5*||e||^2
#define WS_EBF    134148   // 131072 bf16 (= 65536 float slots), 16B aligned
#define WS_CAND   199684   // 65536 uint4, 16B aligned
#define WS_WIN    461828   // 65536 int
#define WS_SORTED 527364   // 65536 int
#define WS_SCODE  592900   // 65536 int

// ---- output float layout ----
#define OFF_Q   0
#define OFF_IND 8388608
#define OFF_NCS 8454144
#define OFF_NEA 8455168
#define OFF_NE  8586240

#define LDST 136  // LDS row stride in bf16 units (128 + 8 pad)

static __device__ __forceinline__ unsigned short f2bf(float f) {
    unsigned u = __float_as_uint(f);
    unsigned r = (u + 0x7FFFu + ((u >> 16) & 1u)) >> 16;  // RTN-even
    return (unsigned short)r;
}

// ============ kernel 1: embed -> bf16 copy + shifted half-norms ============
__global__ __launch_bounds__(64) void k_prep(const float* __restrict__ embed,
                                             unsigned short* __restrict__ ebf,
                                             float* __restrict__ en2) {
    int k = blockIdx.x;
    int l = threadIdx.x;
    float2 v = *(const float2*)&embed[(size_t)k * DIM + l * 2];
    ushort2 b;
    b.x = f2bf(v.x);
    b.y = f2bf(v.y);
    *(ushort2*)&ebf[k * DIM + l * 2] = b;
    float s = v.x * v.x + v.y * v.y;
    #pragma unroll
    for (int off = 32; off; off >>= 1) s += __shfl_xor(s, off);
    if (l == 0) en2[k] = 512.0f - 0.5f * s;
}

// ============ kernel 2: MFMA scoring, 4 candidates per row ============
__global__ __launch_bounds__(256, 2) void k_score(const float* __restrict__ x,
                                                  const unsigned short* __restrict__ ebf,
                                                  const float* __restrict__ en2g,
                                                  uint4* __restrict__ cand) {
    __shared__ unsigned short xbuf[128 * LDST];
    __shared__ unsigned short ebuf[128 * LDST];
    __shared__ float en2s[KCODES];

    const int tid = threadIdx.x;
    const int row0 = blockIdx.x * 128;

    #pragma unroll
    for (int i = 0; i < 4; ++i) en2s[i * 256 + tid] = en2g[i * 256 + tid];

    #pragma unroll
    for (int i = 0; i < 16; ++i) {
        int idx4 = i * 256 + tid;
        int lin = idx4 * 4;
        int r = lin >> 7, d = lin & 127;
        float4 v = *(const float4*)&x[(size_t)(row0 + r) * DIM + d];
        ushort4 b;
        b.x = f2bf(v.x); b.y = f2bf(v.y); b.z = f2bf(v.z); b.w = f2bf(v.w);
        *(ushort4*)&xbuf[r * LDST + d] = b;
    }

    const int lane = tid & 63;
    const int wv = tid >> 6;
    const int ch = wv & 1;
    const int rh = (wv >> 1) * 64;
    const int l15 = lane & 15;
    const int q = lane >> 4;

    float m1[4][4], m2[4][4];
    #pragma unroll
    for (int a = 0; a < 4; ++a)
        #pragma unroll
        for (int b = 0; b < 4; ++b) { m1[a][b] = 0.0f; m2[a][b] = 0.0f; }

    for (int ct = 0; ct < 8; ++ct) {
        const int c0 = ct * 128;
        __syncthreads();
        #pragma unroll
        for (int i = 0; i < 8; ++i) {
            int idx8 = i * 256 + tid;
            int r = idx8 >> 4;
            int d = (idx8 & 15) * 8;
            uint4 v = *(const uint4*)&ebf[(size_t)(c0 + r) * DIM + d];
            *(uint4*)&ebuf[r * LDST + d] = v;
        }
        __syncthreads();

        f32x4 acc[4][4];
        #pragma unroll
        for (int a = 0; a < 4; ++a)
            #pragma unroll
            for (int b = 0; b < 4; ++b) acc[a][b] = (f32x4){0.f, 0.f, 0.f, 0.f};

        #pragma unroll
        for (int ks = 0; ks < 4; ++ks) {
            bf16x8 af[4], bf[4];
            #pragma unroll
            for (int t = 0; t < 4; ++t)
                af[t] = *(const bf16x8*)&xbuf[(rh + t * 16 + l15) * LDST + ks * 32 + q * 8];
            #pragma unroll
            for (int t = 0; t < 4; ++t)
                bf[t] = *(const bf16x8*)&ebuf[(ch * 64 + t * 16 + l15) * LDST + ks * 32 + q * 8];
            #pragma unroll
            for (int rt = 0; rt < 4; ++rt)
                #pragma unroll
                for (int cl = 0; cl < 4; ++cl)
                    acc[rt][cl] = __builtin_amdgcn_mfma_f32_16x16x32_bf16(af[rt], bf[cl],
                                                                          acc[rt][cl], 0, 0, 0);
        }

        #pragma unroll
        for (int cl = 0; cl < 4; ++cl) {
            int code = c0 + ch * 64 + cl * 16 + l15;
            float en = en2s[code];
            unsigned cu = (unsigned)code;
            #pragma unroll
            for (int rt = 0; rt < 4; ++rt)
                #pragma unroll
                for (int rg = 0; rg < 4; ++rg) {
                    float s = acc[rt][cl][rg] + en;
                    float kf = __uint_as_float((__float_as_uint(s) & ~1023u) | cu);
                    float lo = fminf(m1[rt][rg], kf);
                    m1[rt][rg] = fmaxf(m1[rt][rg], kf);
                    m2[rt][rg] = fmaxf(m2[rt][rg], lo);
                }
        }
    }

    __syncthreads();
    float* scratch = (float*)xbuf;
    #pragma unroll
    for (int rt = 0; rt < 4; ++rt)
        #pragma unroll
        for (int rg = 0; rg < 4; ++rg) {
            float a1 = m1[rt][rg], a2 = m2[rt][rg];
            #pragma unroll
            for (int off = 1; off <= 8; off <<= 1) {
                float o1 = __shfl_xor(a1, off);
                float o2 = __shfl_xor(a2, off);
                float lo = fminf(a1, o1);
                a1 = fmaxf(a1, o1);
                a2 = fmaxf(fmaxf(a2, o2), lo);
            }
            if (l15 == 0) {
                int row = rh + rt * 16 + q * 4 + rg;
                scratch[row * 4 + ch * 2 + 0] = a1;
                scratch[row * 4 + ch * 2 + 1] = a2;
            }
        }
    __syncthreads();
    if (tid < 128) {
        const float* p = &scratch[tid * 4];
        uint4 c;
        c.x = __float_as_uint(p[0]) & 1023u;
        c.y = __float_as_uint(p[1]) & 1023u;
        c.z = __float_as_uint(p[2]) & 1023u;
        c.w = __float_as_uint(p[3]) & 1023u;
        cand[row0 + tid] = c;
    }
}

// ============ kernel 3: fp64 rescore ONLY (16 lanes/row), zero atomics ============
// Rounds 4-8: every k_pick variant containing the skewed counts atomicAdd
// (~8000 same-address RMWs on the hot bin) floored at 52-58us with all pipes
// idle. Histogram moved to k_hist (LDS two-level).
__global__ __launch_bounds__(256) void k_pick(const float* __restrict__ x,
                                              const float* __restrict__ embed,
                                              const uint4* __restrict__ cand,
                                              int* __restrict__ win_arr) {
    const int tid = threadIdx.x;
    const int sub = tid & 15;
    const int row = blockIdx.x * 16 + (tid >> 4);

    uint4 cp = cand[row];
    int ci[4] = {(int)cp.x, (int)cp.y, (int)cp.z, (int)cp.w};

    const float* xr = &x[(size_t)row * DIM + sub * 4];
    float4 xa = *(const float4*)xr;
    float4 xb = *(const float4*)(xr + 64);

    double d[4];
    #pragma unroll
    for (int j = 0; j < 4; ++j) {
        const float* er = &embed[(size_t)ci[j] * DIM + sub * 4];
        float4 ea4 = *(const float4*)er;
        float4 eb4 = *(const float4*)(er + 64);
        double t0 = (double)xa.x - (double)ea4.x;
        double t1 = (double)xa.y - (double)ea4.y;
        double t2 = (double)xa.z - (double)ea4.z;
        double t3 = (double)xa.w - (double)ea4.w;
        double t4 = (double)xb.x - (double)eb4.x;
        double t5 = (double)xb.y - (double)eb4.y;
        double t6 = (double)xb.z - (double)eb4.z;
        double t7 = (double)xb.w - (double)eb4.w;
        d[j] = ((t0 * t0 + t1 * t1) + (t2 * t2 + t3 * t3)) +
               ((t4 * t4 + t5 * t5) + (t6 * t6 + t7 * t7));
    }
    #pragma unroll
    for (int off = 1; off <= 8; off <<= 1) {
        #pragma unroll
        for (int j = 0; j < 4; ++j) d[j] += __shfl_xor(d[j], off);
    }

    int win = ci[0];
    double dw = d[0];
    #pragma unroll
    for (int j = 1; j < 4; ++j) {
        bool b = (d[j] < dw) || (d[j] == dw && ci[j] < win);
        dw = b ? d[j] : dw;
        win = b ? ci[j] : win;
    }

    if (sub == 0) win_arr[row] = win;
}

// ============ kernel 3b: two-level histogram (skew-proof) ============
// 256 blocks x 256 rows; LDS histogram absorbs same-address serialization
// (<=256 ds-adds on the hot bin); global flush <=256 atomics per bin total.
__global__ __launch_bounds__(256) void k_hist(const int* __restrict__ win_arr,
                                              float* __restrict__ counts) {
    __shared__ unsigned h[KCODES];
    const int t = threadIdx.x;
    #pragma unroll
    for (int i = 0; i < 4; ++i) h[i * 256 + t] = 0u;
    __syncthreads();
    atomicAdd(&h[win_arr[blockIdx.x * 256 + t]], 1u);
    __syncthreads();
    #pragma unroll
    for (int i = 0; i < 4; ++i) {
        unsigned c = h[i * 256 + t];
        if (c) atomicAdd(&counts[i * 256 + t], (float)c);
    }
}

// ============ kernel 3c: quantize gather + ind write ============
__global__ __launch_bounds__(256) void k_quant(const float* __restrict__ embed,
                                               const int* __restrict__ win_arr,
                                               float* __restrict__ out) {
    const int tid = threadIdx.x;
    const int lane = tid & 63;
    const int wv = tid >> 6;
    const int rowb = blockIdx.x * 64 + wv * 16;

    if (tid < 64) {
        int r = blockIdx.x * 64 + tid;
        out[OFF_IND + r] = (float)win_arr[r];
    }

    #pragma unroll 4
    for (int i = 0; i < 16; ++i) {
        int row = rowb + i;
        int w = win_arr[row];  // wave-uniform
        float2 v = *(const float2*)&embed[(size_t)w * DIM + lane * 2];
        *(float2*)&out[OFF_Q + (size_t)row * DIM + lane * 2] = v;
    }
}

// ============ kernel 4: shuffle-scan offsets + new_cluster_size + total ============
__global__ __launch_bounds__(1024) void k_offsets(const float* __restrict__ cs,
                                                  float* __restrict__ out,
                                                  float* __restrict__ ws) {
    __shared__ int wsum[16];
    __shared__ float wtot[16];
    const float* counts = ws + WS_COUNTS;
    int* ioff = (int*)(ws + WS_IOFF);

    int t = threadIdx.x;
    int lane = t & 63, w = t >> 6;
    float cf = counts[t];
    int c = (int)cf;
    float ncs = cs[t] * 0.99f + 0.01f * cf;
    out[OFF_NCS + t] = ncs;

    int v = c;
    #pragma unroll
    for (int off = 1; off < 64; off <<= 1) {
        int o = __shfl_up(v, off);
        if (lane >= off) v += o;
    }
    float nf = ncs;
    #pragma unroll
    for (int off = 32; off; off >>= 1) nf += __shfl_xor(nf, off);

    if (lane == 63) wsum[w] = v;
    if (lane == 0) wtot[w] = nf;
    __syncthreads();

    int base = 0;
    for (int i = 0; i < w; ++i) base += wsum[i];
    ioff[t] = base + v - c;

    if (t == 0) {
        float tt = 0.f;
        for (int i = 0; i < 16; ++i) tt += wtot[i];
        ws[WS_TOTAL] = tt;
    }
}

// ============ kernel 5: scatter rows into code-sorted order ============
__global__ __launch_bounds__(256) void k_sortscatter(const int* __restrict__ win_arr,
                                                     int* __restrict__ ioff,
                                                     int* __restrict__ sorted,
                                                     int* __restrict__ scode) {
    int row = blockIdx.x * 256 + threadIdx.x;
    int w = win_arr[row];
    int pos = atomicAdd(&ioff[w], 1);
    sorted[pos] = row;
    scode[pos] = w;
}

// ============ kernel 6: chunked run-length segment sum (skew-proof) ============
__global__ __launch_bounds__(256) void k_segsum(const float* __restrict__ x,
                                                const int* __restrict__ sorted,
                                                const int* __restrict__ scode,
                                                float* __restrict__ esum) {
    const int lane = threadIdx.x & 63;
    const int wv = threadIdx.x >> 6;
    const int base = blockIdx.x * 64 + wv * 16;

    int p = base + (lane & 15);
    int srow = sorted[p];
    int sc = scode[p];

    float ax = 0.f, ay = 0.f;
    int cur = __shfl(sc, 0);

    #pragma unroll
    for (int j = 0; j < 16; ++j) {
        int row = __shfl(srow, j);
        int c = __shfl(sc, j);
        if (c != cur) {
            atomicAdd(&esum[cur * DIM + lane * 2], ax);
            atomicAdd(&esum[cur * DIM + lane * 2 + 1], ay);
            ax = 0.f; ay = 0.f;
            cur = c;
        }
        float2 v = *(const float2*)&x[(size_t)row * DIM + lane * 2];
        ax += v.x;
        ay += v.y;
    }
    atomicAdd(&esum[cur * DIM + lane * 2], ax);
    atomicAdd(&esum[cur * DIM + lane * 2 + 1], ay);
}

// ============ kernel 7: new_embed_avg + new_embed ============
__global__ __launch_bounds__(256) void k_embed(const float* __restrict__ ea,
                                               const float* __restrict__ ws,
                                               float* __restrict__ out) {
    int i = blockIdx.x * 256 + threadIdx.x;
    int k = i >> 7;
    float nea = ea[i] * 0.99f + 0.01f * ws[WS_ESUM + i];
    out[OFF_NEA + i] = nea;
    float total = ws[WS_TOTAL];
    float ncs = out[OFF_NCS + k];
    float sm = (ncs + 1e-5f) / (total + 1024.0f * 1e-5f);
    out[OFF_NE + i] = nea / (sm * total);
}

extern "C" void kernel_launch(void* const* d_in, const int* in_sizes, int n_in,
                              void* d_out, int out_size, void* d_ws, size_t ws_size,
                              hipStream_t stream) {
    const float* x     = (const float*)d_in[0];
    const float* embed = (const float*)d_in[1];
    const float* cs    = (const float*)d_in[2];
    const float* ea    = (const float*)d_in[3];
    float* out = (float*)d_out;
    float* ws  = (float*)d_ws;

    hipMemsetAsync(d_ws, 0, (size_t)(1024 + 131072) * 4, stream);

    k_prep<<<KCODES, 64, 0, stream>>>(embed, (unsigned short*)(ws + WS_EBF), ws + WS_ENORM2);
    k_score<<<NROWS / 128, 256, 0, stream>>>(x, (const unsigned short*)(ws + WS_EBF),
                                             ws + WS_ENORM2, (uint4*)(ws + WS_CAND));
    k_pick<<<NROWS / 16, 256, 0, stream>>>(x, embed, (const uint4*)(ws + WS_CAND),
                                           (int*)(ws + WS_WIN));
    k_hist<<<NROWS / 256, 256, 0, stream>>>((const int*)(ws + WS_WIN), ws + WS_COUNTS);
    k_quant<<<NROWS / 64, 256, 0, stream>>>(embed, (const int*)(ws + WS_WIN), out);
    k_offsets<<<1, 1024, 0, stream>>>(cs, out, ws);
    k_sortscatter<<<NROWS / 256, 256, 0, stream>>>((const int*)(ws + WS_WIN),
                                                   (int*)(ws + WS_IOFF),
                                                   (int*)(ws + WS_SORTED),
                                                   (int*)(ws + WS_SCODE));
    k_segsum<<<1024, 256, 0, stream>>>(x, (const int*)(ws + WS_SORTED),
                                       (const int*)(ws + WS_SCODE), ws + WS_ESUM);
    k_embed<<<131072 / 256, 256, 0, stream>>>(ea, ws, out);
}